// Round 16
// baseline (521.819 us; speedup 1.0000x reference)
//
#include <hip/hip_runtime.h>

// ---------- types ----------
typedef short s16x8 __attribute__((ext_vector_type(8)));   // 8 bf16 (4 VGPRs)
typedef float f32x4 __attribute__((ext_vector_type(4)));

static __device__ __forceinline__ unsigned short f2bf(float f) {
  unsigned u = __builtin_bit_cast(unsigned, f);
  return (unsigned short)((u + 0x7FFFu + ((u >> 16) & 1u)) >> 16);   // RNE; finite
}

// async global->LDS, 16B per lane; LDS dst is wave-uniform base + lane*16
#define GLL16(G, L) __builtin_amdgcn_global_load_lds( \
    (const __attribute__((address_space(1))) void*)(G), \
    (__attribute__((address_space(3))) void*)(L), 16, 0, 0)

#define KD 512
// B=16, T=512, C=19, E=512, H=8, HD=64; groups = 8192, rows = 155648 = 608*256.
// Fragment layout: frag (tile16, ktile32) = 1 KB: lane lf = (row&15) + 16*jc holds
// 16 B (8 bf16) of [row][ktile*32 + jc*8]. MFMA A/B reads are lane*16-linear.

// ---------- kernel: eeg fp32 -> bf16 fragment layout ----------
__global__ __launch_bounds__(256)
void k_conva(const float* __restrict__ src, unsigned short* __restrict__ dst) {
  int gid = blockIdx.x * 256 + threadIdx.x;
  int mt = gid >> 10, slot = gid & 1023;
  int kt = slot >> 6, lf = slot & 63;
  int row = mt * 16 + (lf & 15);
  int jc  = lf >> 4;
  const float* p = src + (long)row * KD + kt * 32 + jc * 8;
  float4 v0 = *(const float4*)p;
  float4 v1 = *(const float4*)(p + 4);
  s16x8 o;
  o[0]=(short)f2bf(v0.x); o[1]=(short)f2bf(v0.y); o[2]=(short)f2bf(v0.z); o[3]=(short)f2bf(v0.w);
  o[4]=(short)f2bf(v1.x); o[5]=(short)f2bf(v1.y); o[6]=(short)f2bf(v1.z); o[7]=(short)f2bf(v1.w);
  *(s16x8*)(dst + ((long)mt * 16 + kt) * 512 + (long)lf * 8) = o;
}

// ---------- kernel: weights fp32 -> bf16 fragment layout (rows 0..511 wq, 512..1023 wk) ----------
__global__ __launch_bounds__(256)
void k_convw(const float* __restrict__ wq, const float* __restrict__ wk,
             unsigned short* __restrict__ Wf) {
  int gid = blockIdx.x * 256 + threadIdx.x;   // 65536 threads
  int nt = gid >> 10, slot = gid & 1023;
  int kt = slot >> 6, lf = slot & 63;
  int f  = nt * 16 + (lf & 15);
  int jc = lf >> 4;
  const float* p = ((f < 512) ? (wq + (long)f * KD) : (wk + (long)(f - 512) * KD)) + kt * 32 + jc * 8;
  float4 v0 = *(const float4*)p;
  float4 v1 = *(const float4*)(p + 4);
  s16x8 o;
  o[0]=(short)f2bf(v0.x); o[1]=(short)f2bf(v0.y); o[2]=(short)f2bf(v0.z); o[3]=(short)f2bf(v0.w);
  o[4]=(short)f2bf(v1.x); o[5]=(short)f2bf(v1.y); o[6]=(short)f2bf(v1.z); o[7]=(short)f2bf(v1.w);
  *(s16x8*)(Wf + ((long)nt * 16 + kt) * 512 + (long)lf * 8) = o;
}

// ---------- kernel: QK = A @ [Wq^T | Wk^T] + bias ----------
// v11: 256x256-tile 8-wave counted-vmcnt pipeline (T3+T4+T5; m218/m201 regime).
// 2-phase loops are stage+drain+barrier-bound (~72%, m233) at ANY occupancy --
// R9..R15 all pinned ~240-290. This is the only structure measured to break it.
// 3 x 32KB LDS buffers, depth-2: STAGE(t+2) at top; s_waitcnt vmcnt(4) (counted,
// t+2's 4 loads stay in flight) + raw s_barrier w/ memory clobber (NOT
// __syncthreads - that drains vmcnt(0); NOT sched_barrier(0) - R13's regression).
// Frag layout (pre-swizzled global) replaces the template's st_16x32: LDS reads
// are lane*16-linear, conflict-free by construction.
__global__ __launch_bounds__(512, 2)
void k_gemm(const unsigned short* __restrict__ Af, const unsigned short* __restrict__ Wf,
            const float* __restrict__ bq, const float* __restrict__ bk,
            unsigned short* __restrict__ QK) {
  __shared__ unsigned short Abuf[3][16 * 512];   // 16 m-frags (16 KB) per buffer
  __shared__ unsigned short Bbuf[3][16 * 512];   // 16 n-frags per buffer

  const int tid  = threadIdx.x;
  const int lane = tid & 63;
  const int wid  = tid >> 6;          // 0..7
  const int wr   = wid >> 2;          // wave M-row 0..1 (owns 128 rows)
  const int wc   = wid & 3;           // wave N-col 0..3 (owns 64 cols)
  const int rlo  = lane & 15, rhi = lane >> 4;

  // XCD-chunked swizzle; grid = 608*4 = 2432 (%8==0 -> bijective). 4 consecutive
  // L share one mb -> 256-row A panel L2-resident per XCD run.
  const int cpx = gridDim.x >> 3;
  const int L   = (blockIdx.x & 7) * cpx + (blockIdx.x >> 3);
  const int mb  = L >> 2;             // 0..607
  const int bn  = L & 3;              // 0..3 (256-col block)

  // staging: waves 0-3 stage A (4 frags each), waves 4-7 stage B (4 frags each)
#define STAGE(T, BUF) do { \
    if (wid < 4) { \
      _Pragma("unroll") for (int s = 0; s < 4; ++s) { \
        int msub = wid * 4 + s; \
        const unsigned short* g = Af + ((long)(mb * 16 + msub) * 16 + (T)) * 512 + lane * 8; \
        GLL16(g, &Abuf[(BUF)][msub * 512]); \
      } \
    } else { \
      _Pragma("unroll") for (int s = 0; s < 4; ++s) { \
        int nsub = (wid - 4) * 4 + s; \
        const unsigned short* g = Wf + ((long)(bn * 16 + nsub) * 16 + (T)) * 512 + lane * 8; \
        GLL16(g, &Bbuf[(BUF)][nsub * 512]); \
      } \
    } \
  } while (0)

  f32x4 acc[8][4] = {};   // static indices only (full unroll below)

  // prologue: tiles 0,1 in flight; wait tile 0 (4 oldest of 8), barrier
  STAGE(0, 0);
  STAGE(1, 1);
  asm volatile("s_waitcnt vmcnt(4)" ::: "memory");
  asm volatile("s_barrier" ::: "memory");

  int cur = 0;
#pragma unroll 1
  for (int t = 0; t < 16; ++t) {
    if (t < 14) {
      int stg = cur + 2; if (stg >= 3) stg -= 3;
      STAGE(t + 2, stg);              // 4 GLL16/wave, fly through 2 compute steps
    }

    s16x8 bfr[4];
#pragma unroll
    for (int n = 0; n < 4; ++n)
      bfr[n] = *(const s16x8*)&Bbuf[cur][(wc * 4 + n) * 512 + lane * 8];

    // phase A: m-frags 0..3
    {
      s16x8 af[4];
#pragma unroll
      for (int m = 0; m < 4; ++m)
        af[m] = *(const s16x8*)&Abuf[cur][(wr * 8 + m) * 512 + lane * 8];
      __builtin_amdgcn_s_setprio(1);
#pragma unroll
      for (int m = 0; m < 4; ++m)
#pragma unroll
        for (int n = 0; n < 4; ++n)
          acc[m][n] = __builtin_amdgcn_mfma_f32_16x16x32_bf16(af[m], bfr[n], acc[m][n], 0, 0, 0);
      __builtin_amdgcn_s_setprio(0);
    }
    // phase B: m-frags 4..7
    {
      s16x8 af[4];
#pragma unroll
      for (int m = 0; m < 4; ++m)
        af[m] = *(const s16x8*)&Abuf[cur][(wr * 8 + 4 + m) * 512 + lane * 8];
      __builtin_amdgcn_s_setprio(1);
#pragma unroll
      for (int m = 0; m < 4; ++m)
#pragma unroll
        for (int n = 0; n < 4; ++n)
          acc[4 + m][n] = __builtin_amdgcn_mfma_f32_16x16x32_bf16(af[m], bfr[n], acc[4 + m][n], 0, 0, 0);
      __builtin_amdgcn_s_setprio(0);
    }

    if (t < 14)      asm volatile("s_waitcnt vmcnt(4)" ::: "memory");  // t+1 landed; t+2 flying
    else if (t == 14) asm volatile("s_waitcnt vmcnt(0)" ::: "memory"); // final drain
    if (t < 15)      asm volatile("s_barrier" ::: "memory");
    cur += 1; if (cur >= 3) cur -= 3;
  }
#undef STAGE

  // ---- epilogue: bias + bf16 store ----
#pragma unroll
  for (int n = 0; n < 4; ++n) {
    int colg = bn * 256 + wc * 64 + n * 16 + rlo;
    float bias = (colg < 512) ? bq[colg] : bk[colg - 512];
#pragma unroll
    for (int m = 0; m < 8; ++m) {
      long rl = (long)mb * 256 + wr * 128 + m * 16 + (rhi << 2);
#pragma unroll
      for (int j = 0; j < 4; ++j)
        QK[(rl + j) * 1024 + colg] = f2bf(acc[m][n][j] + bias);
    }
  }
}

// ---------- kernel: per-group attention (swapped-QK^T, row-local softmax) ----------
// v3 (R13, verified): mfma(K,Q) puts q-row in lane; reduction = in-lane + 2 shfl_xor.
__global__ __launch_bounds__(256, 4)
void k_attn(const unsigned short* __restrict__ QK, float* __restrict__ acc, int g0) {
  __shared__ unsigned short Qs[19][1032];   // padded stride
  __shared__ float red[4];

  const int tid  = threadIdx.x;
  const int lane = tid & 63;
  const int wid  = tid >> 6;
  const long gl  = blockIdx.x;

  const unsigned short* src = QK + gl * 19 * 1024;
  for (int c = tid; c < 2432; c += 256) {
    int row = c >> 7, c8 = (c & 127) << 3;
    *(s16x8*)&Qs[row][c8] = *(const s16x8*)(src + row * 1024 + c8);
  }
  __syncthreads();

  const int rlo = lane & 15, rhi = lane >> 4;
  const s16x8 z8 = {};
  float psum = 0.f;

#pragma unroll
  for (int hh = 0; hh < 2; ++hh) {
    const int h = wid * 2 + hh;
    f32x4 s[2][2] = {};   // [k-tile mi][q-tile nj]
#pragma unroll
    for (int ks = 0; ks < 2; ++ks) {
      s16x8 qa[2], kb[2];
#pragma unroll
      for (int mi = 0; mi < 2; ++mi) {
        int r = mi * 16 + rlo;
        qa[mi] = (r < 19) ? *(const s16x8*)&Qs[r][h * 64 + ks * 32 + rhi * 8] : z8;
        kb[mi] = (r < 19) ? *(const s16x8*)&Qs[r][512 + h * 64 + ks * 32 + rhi * 8] : z8;
      }
#pragma unroll
      for (int mi = 0; mi < 2; ++mi)
#pragma unroll
        for (int nj = 0; nj < 2; ++nj)
          s[mi][nj] = __builtin_amdgcn_mfma_f32_16x16x32_bf16(kb[mi], qa[nj], s[mi][nj], 0, 0, 0);
    }

    // lane view: q = nj*16 + rlo; k = mi*16 + rhi*4 + j
#pragma unroll
    for (int nj = 0; nj < 2; ++nj) {
      const int q = nj * 16 + rlo;
      const bool qv = (q < 19);
      const bool wv = (rhi == 0);          // k=16..18 live on rhi==0
      float v0 = s[0][nj][0] * 0.125f;
      float v1 = s[0][nj][1] * 0.125f;
      float v2 = s[0][nj][2] * 0.125f;
      float v3 = s[0][nj][3] * 0.125f;
      float w0 = s[1][nj][0] * 0.125f;
      float w1 = s[1][nj][1] * 0.125f;
      float w2 = s[1][nj][2] * 0.125f;
      float mm = fmaxf(fmaxf(v0, v1), fmaxf(v2, v3));
      if (wv) mm = fmaxf(mm, fmaxf(fmaxf(w0, w1), w2));
      mm = fmaxf(mm, __shfl_xor(mm, 16));
      mm = fmaxf(mm, __shfl_xor(mm, 32));
      float e0 = __expf(v0 - mm), e1 = __expf(v1 - mm);
      float e2 = __expf(v2 - mm), e3 = __expf(v3 - mm);
      float se = e0 + e1 + e2 + e3;
      int k0 = rhi * 4;
      float ue = ((k0 > q) ? e0 : 0.f) + ((k0 + 1 > q) ? e1 : 0.f)
               + ((k0 + 2 > q) ? e2 : 0.f) + ((k0 + 3 > q) ? e3 : 0.f);
      if (wv) {
        float f0 = __expf(w0 - mm), f1 = __expf(w1 - mm), f2 = __expf(w2 - mm);
        se += f0 + f1 + f2;
        ue += ((16 > q) ? f0 : 0.f) + ((17 > q) ? f1 : 0.f) + ((18 > q) ? f2 : 0.f);
      }
      se += __shfl_xor(se, 16); se += __shfl_xor(se, 32);
      ue += __shfl_xor(ue, 16); ue += __shfl_xor(ue, 32);
      if (qv && rhi == 0) psum += ue / se;
    }
  }

  psum += __shfl_xor(psum, 1);
  psum += __shfl_xor(psum, 2);
  psum += __shfl_xor(psum, 4);
  psum += __shfl_xor(psum, 8);
  psum += __shfl_xor(psum, 16);
  psum += __shfl_xor(psum, 32);
  if (lane == 0) red[wid] = psum;
  __syncthreads();
  if (tid == 0) {
    int b = (g0 + (int)blockIdx.x) >> 9;
    atomicAdd(&acc[b], red[0] + red[1] + red[2] + red[3]);
  }
}

// ---------- kernel: finalize out[b] = clip(acc[b] / (8*171*512), 0, 1) ----------
__global__ void k_fin(const float* __restrict__ acc, float* __restrict__ out) {
  int t = threadIdx.x;
  if (t < 16) {
    float v = acc[t] * (1.0f / 700416.0f);
    out[t] = fminf(1.0f, fmaxf(0.0f, v));
  }
}

// ---------- host ----------
extern "C" void kernel_launch(void* const* d_in, const int* in_sizes, int n_in,
                              void* d_out, int out_size, void* d_ws, size_t ws_size,
                              hipStream_t stream) {
  const float* eeg = (const float*)d_in[0];
  const float* wq  = (const float*)d_in[1];
  const float* wk  = (const float*)d_in[2];
  const float* bq  = (const float*)d_in[3];
  const float* bk  = (const float*)d_in[4];
  float* out = (float*)d_out;

  char* ws = (char*)d_ws;
  unsigned short* Wf = (unsigned short*)ws;          // 1 MiB frag-layout weights
  float* acc = (float*)(ws + (1 << 20));             // 64 B accumulators
  long off = (1 << 20) + 256;

  // per-group: Af 19456 B, QK 38912 B. Chunk must keep rows % 256 == 0:
  // G multiple of 256 groups (256*19 = 4864 rows = 19 m256-tiles).
  long avail = (long)ws_size - off;
  long G = avail / 58368;
  G = (G / 256) * 256;
  if (G > 8192) G = 8192;
  if (G < 256) G = 256;
  unsigned short* Afb = (unsigned short*)(ws + off);
  unsigned short* QKb = (unsigned short*)(ws + off + G * 19456L);

  hipMemsetAsync(acc, 0, 64, stream);
  k_convw<<<256, 256, 0, stream>>>(wq, wk, Wf);

  for (int g0 = 0; g0 < 8192; g0 += (int)G) {
    int cg = 8192 - g0; if (cg > (int)G) cg = (int)G;
    int rows   = cg * 19;            // cg multiple of 256 -> rows multiple of 4864
    int mtiles = rows / 16;
    k_conva<<<mtiles * 4, 256, 0, stream>>>(eeg + (long)g0 * 19 * KD, Afb);
    k_gemm<<<(rows / 256) * 4, 512, 0, stream>>>(Afb, Wf, bq, bk, QKb);
    k_attn<<<cg, 256, 0, stream>>>(QKb, acc, g0);
  }
  k_fin<<<1, 64, 0, stream>>>(acc, out);
}

// Round 17
// 423.924 us; speedup vs baseline: 1.2309x; 1.2309x over previous
//
#include <hip/hip_runtime.h>

// ---------- types ----------
typedef short s16x8 __attribute__((ext_vector_type(8)));   // 8 bf16 (4 VGPRs)
typedef float f32x4 __attribute__((ext_vector_type(4)));

static __device__ __forceinline__ unsigned short f2bf(float f) {
  unsigned u = __builtin_bit_cast(unsigned, f);
  return (unsigned short)((u + 0x7FFFu + ((u >> 16) & 1u)) >> 16);   // RNE; finite
}

// async global->LDS, 16B per lane; LDS dst is wave-uniform base + lane*16
#define GLL16(G, L) __builtin_amdgcn_global_load_lds( \
    (const __attribute__((address_space(1))) void*)(G), \
    (__attribute__((address_space(3))) void*)(L), 16, 0, 0)

#define KD 512
// B=16, T=512, C=19, E=512, H=8, HD=64; groups = 8192, rows = 155648 = 512*304.
// Fragment layout: frag (tile16, ktile32) = 1 KB: lane lf = (row&15) + 16*jc holds
// 16 B (8 bf16) of [row][ktile*32 + jc*8]. MFMA A/B reads are lane*16-linear.

// ---------- kernel: eeg fp32 -> bf16 fragment layout ----------
__global__ __launch_bounds__(256)
void k_conva(const float* __restrict__ src, unsigned short* __restrict__ dst) {
  int gid = blockIdx.x * 256 + threadIdx.x;
  int mt = gid >> 10, slot = gid & 1023;
  int kt = slot >> 6, lf = slot & 63;
  int row = mt * 16 + (lf & 15);
  int jc  = lf >> 4;
  const float* p = src + (long)row * KD + kt * 32 + jc * 8;
  float4 v0 = *(const float4*)p;
  float4 v1 = *(const float4*)(p + 4);
  s16x8 o;
  o[0]=(short)f2bf(v0.x); o[1]=(short)f2bf(v0.y); o[2]=(short)f2bf(v0.z); o[3]=(short)f2bf(v0.w);
  o[4]=(short)f2bf(v1.x); o[5]=(short)f2bf(v1.y); o[6]=(short)f2bf(v1.z); o[7]=(short)f2bf(v1.w);
  *(s16x8*)(dst + ((long)mt * 16 + kt) * 512 + (long)lf * 8) = o;
}

// ---------- kernel: weights fp32 -> bf16 fragment layout (rows 0..511 wq, 512..1023 wk) ----------
__global__ __launch_bounds__(256)
void k_convw(const float* __restrict__ wq, const float* __restrict__ wk,
             unsigned short* __restrict__ Wf) {
  int gid = blockIdx.x * 256 + threadIdx.x;   // 65536 threads
  int nt = gid >> 10, slot = gid & 1023;
  int kt = slot >> 6, lf = slot & 63;
  int f  = nt * 16 + (lf & 15);
  int jc = lf >> 4;
  const float* p = ((f < 512) ? (wq + (long)f * KD) : (wk + (long)(f - 512) * KD)) + kt * 32 + jc * 8;
  float4 v0 = *(const float4*)p;
  float4 v1 = *(const float4*)(p + 4);
  s16x8 o;
  o[0]=(short)f2bf(v0.x); o[1]=(short)f2bf(v0.y); o[2]=(short)f2bf(v0.z); o[3]=(short)f2bf(v0.w);
  o[4]=(short)f2bf(v1.x); o[5]=(short)f2bf(v1.y); o[6]=(short)f2bf(v1.z); o[7]=(short)f2bf(v1.w);
  *(s16x8*)(Wf + ((long)nt * 16 + kt) * 512 + (long)lf * 8) = o;
}

// ---------- fused kernel: projection (R9-structure GEMM) + scores + softmax ----------
// Block = (mb, head h): rows [mb*304, +304) = 19 m-frags = EXACTLY 16 groups; cols =
// head h's Q|K = 8 n-frags (4 Q + 4 K via Wf frag remap). QK matrix never touches HBM:
// C (304x128 bf16 + bias) goes to LDS (80 KB), then attn-v3 swapped softmax per group,
// one atomicAdd per block. Projection loop is R9's proven 2-barrier gload_lds form;
// waves 4x2: wave (wm,wn) owns 5 m-frags x 4 n-frags (20 MFMA : 9 LDS-reads/step).
__global__ __launch_bounds__(512, 2)
void k_fgemm(const unsigned short* __restrict__ Af, const unsigned short* __restrict__ Wf,
             const float* __restrict__ bq, const float* __restrict__ bk,
             float* __restrict__ oacc) {
  __shared__ unsigned short Sbuf[27 * 512];   // A frags 0..18, B frags 19..26 (27 KB)
  __shared__ unsigned short CL[320 * 136];    // C rows(+pad) x cols(Q:0..63 | K:64..127), 87 KB
  __shared__ float red[8];

  const int tid  = threadIdx.x;
  const int lane = tid & 63;
  const int wid  = tid >> 6;        // 0..7
  const int wm   = wid >> 1;        // 0..3: owns m-frags wm*5..wm*5+4 (wm=3: 4 real + dummy)
  const int wn   = wid & 1;         // 0..1: owns n-frags wn*4..wn*4+3
  const int rlo  = lane & 15, rhi = lane >> 4;

  // XCD-chunked swizzle: grid 4096 (%8==0, bijective); h fastest within an XCD run
  // -> the 8 head-blocks of one mb are temporally adjacent on ONE XCD (A panel L2-hit).
  const int cpx = gridDim.x >> 3;
  const int L   = ((int)blockIdx.x & 7) * cpx + ((int)blockIdx.x >> 3);
  const int mb  = L >> 3;           // 0..511
  const int h   = L & 7;
  const long mbase = (long)mb * 19;

#define STAGE(T) do { \
    { int m0 = wid * 2; \
      GLL16(Af + ((mbase + m0) * 16 + (T)) * 512 + lane * 8, &Sbuf[m0 * 512]); \
      GLL16(Af + ((mbase + m0 + 1) * 16 + (T)) * 512 + lane * 8, &Sbuf[(m0 + 1) * 512]); } \
    if (wid < 3) \
      GLL16(Af + ((mbase + 16 + wid) * 16 + (T)) * 512 + lane * 8, &Sbuf[(16 + wid) * 512]); \
    if (wid >= 4) { \
      int ns  = (wid - 4) * 2; \
      int nt0 = (ns < 4)     ? (h * 4 + ns)          : (32 + h * 4 + ns - 4); \
      int nt1 = (ns + 1 < 4) ? (h * 4 + ns + 1)      : (32 + h * 4 + ns - 3); \
      GLL16(Wf + ((long)nt0 * 16 + (T)) * 512 + lane * 8, &Sbuf[(19 + ns) * 512]); \
      GLL16(Wf + ((long)nt1 * 16 + (T)) * 512 + lane * 8, &Sbuf[(19 + ns + 1) * 512]); \
    } \
  } while (0)

  f32x4 acc[5][4] = {};
  STAGE(0);
  __syncthreads();   // vmcnt(0) drain: buffer ready

#pragma unroll 1
  for (int t = 0; t < 16; ++t) {
    s16x8 af[5], bf[4];
#pragma unroll
    for (int i = 0; i < 5; ++i) {
      int fi = wm * 5 + i; fi = (fi > 18) ? 0 : fi;   // wm=3 5th row: dummy (discarded)
      af[i] = *(const s16x8*)&Sbuf[fi * 512 + lane * 8];
    }
#pragma unroll
    for (int n = 0; n < 4; ++n)
      bf[n] = *(const s16x8*)&Sbuf[(19 + wn * 4 + n) * 512 + lane * 8];
#pragma unroll
    for (int i = 0; i < 5; ++i)
#pragma unroll
      for (int n = 0; n < 4; ++n)
        acc[i][n] = __builtin_amdgcn_mfma_f32_16x16x32_bf16(af[i], bf[n], acc[i][n], 0, 0, 0);
    if (t < 15) {
      __syncthreads();       // all reads of buffer done
      STAGE(t + 1);
      __syncthreads();       // drain: next buffer ready
    }
  }
#undef STAGE

  // ---- C -> LDS with bias (row-major [320][136]: rows 16B-aligned, writes ~2-way) ----
  float bias[4];
#pragma unroll
  for (int n = 0; n < 4; ++n) {
    int c = wn * 64 + n * 16 + rlo;
    bias[n] = (wn == 0) ? bq[h * 64 + c] : bk[h * 64 + (c - 64)];
  }
#pragma unroll
  for (int i = 0; i < 5; ++i) {
    int fi = wm * 5 + i;
    if (fi <= 18) {
#pragma unroll
      for (int n = 0; n < 4; ++n) {
        int c = wn * 64 + n * 16 + rlo;
#pragma unroll
        for (int j = 0; j < 4; ++j)
          CL[(fi * 16 + rhi * 4 + j) * 136 + c] = f2bf(acc[i][n][j] + bias[n]);
      }
    }
  }
  __syncthreads();

  // ---- scores + softmax (attn-v3 math): wave handles groups {2*wid, 2*wid+1} ----
  float psum = 0.f;
#pragma unroll
  for (int gg = 0; gg < 2; ++gg) {
    const int g19 = (wid * 2 + gg) * 19;
    f32x4 s[2][2] = {};   // [k-tile mi][q-tile nj]
#pragma unroll
    for (int ks = 0; ks < 2; ++ks) {
      s16x8 kb[2], qa[2];
#pragma unroll
      for (int mi = 0; mi < 2; ++mi) {
        kb[mi] = *(const s16x8*)&CL[(g19 + mi * 16 + rlo) * 136 + 64 + ks * 32 + rhi * 8];
        qa[mi] = *(const s16x8*)&CL[(g19 + mi * 16 + rlo) * 136 + ks * 32 + rhi * 8];
      }
#pragma unroll
      for (int mi = 0; mi < 2; ++mi)
#pragma unroll
        for (int nj = 0; nj < 2; ++nj)
          s[mi][nj] = __builtin_amdgcn_mfma_f32_16x16x32_bf16(kb[mi], qa[nj], s[mi][nj], 0, 0, 0);
    }
    // lane view: q = nj*16 + rlo; k = mi*16 + rhi*4 + j. Garbage (k>=19 / q>=19 /
    // pad rows) never enters mm/se/ue: guarded slots, and xor16/32 preserves rlo.
#pragma unroll
    for (int nj = 0; nj < 2; ++nj) {
      const int q = nj * 16 + rlo;
      const bool qv = (q < 19);
      const bool wv = (rhi == 0);
      float v0 = s[0][nj][0] * 0.125f;
      float v1 = s[0][nj][1] * 0.125f;
      float v2 = s[0][nj][2] * 0.125f;
      float v3 = s[0][nj][3] * 0.125f;
      float w0 = s[1][nj][0] * 0.125f;
      float w1 = s[1][nj][1] * 0.125f;
      float w2 = s[1][nj][2] * 0.125f;
      float mm = fmaxf(fmaxf(v0, v1), fmaxf(v2, v3));
      if (wv) mm = fmaxf(mm, fmaxf(fmaxf(w0, w1), w2));
      mm = fmaxf(mm, __shfl_xor(mm, 16));
      mm = fmaxf(mm, __shfl_xor(mm, 32));
      float e0 = __expf(v0 - mm), e1 = __expf(v1 - mm);
      float e2 = __expf(v2 - mm), e3 = __expf(v3 - mm);
      float se = e0 + e1 + e2 + e3;
      int k0 = rhi * 4;
      float ue = ((k0 > q) ? e0 : 0.f) + ((k0 + 1 > q) ? e1 : 0.f)
               + ((k0 + 2 > q) ? e2 : 0.f) + ((k0 + 3 > q) ? e3 : 0.f);
      if (wv) {
        float f0 = __expf(w0 - mm), f1 = __expf(w1 - mm), f2 = __expf(w2 - mm);
        se += f0 + f1 + f2;
        ue += ((16 > q) ? f0 : 0.f) + ((17 > q) ? f1 : 0.f) + ((18 > q) ? f2 : 0.f);
      }
      se += __shfl_xor(se, 16); se += __shfl_xor(se, 32);
      ue += __shfl_xor(ue, 16); ue += __shfl_xor(ue, 32);
      if (qv && rhi == 0) psum += ue / se;
    }
  }

  psum += __shfl_xor(psum, 1);
  psum += __shfl_xor(psum, 2);
  psum += __shfl_xor(psum, 4);
  psum += __shfl_xor(psum, 8);
  psum += __shfl_xor(psum, 16);
  psum += __shfl_xor(psum, 32);
  if (lane == 0) red[wid] = psum;
  __syncthreads();
  if (tid == 0) {
    // all 16 groups of this block share one batch: b = mb*16/512 = mb>>5
    atomicAdd(&oacc[mb >> 5], red[0] + red[1] + red[2] + red[3]
                            + red[4] + red[5] + red[6] + red[7]);
  }
}

// ---------- kernel: finalize out[b] = clip(acc[b] / (8*171*512), 0, 1) ----------
__global__ void k_fin(const float* __restrict__ acc, float* __restrict__ out) {
  int t = threadIdx.x;
  if (t < 16) {
    float v = acc[t] * (1.0f / 700416.0f);
    out[t] = fminf(1.0f, fmaxf(0.0f, v));
  }
}

// ---------- host ----------
extern "C" void kernel_launch(void* const* d_in, const int* in_sizes, int n_in,
                              void* d_out, int out_size, void* d_ws, size_t ws_size,
                              hipStream_t stream) {
  const float* eeg = (const float*)d_in[0];
  const float* wq  = (const float*)d_in[1];
  const float* wk  = (const float*)d_in[2];
  const float* bq  = (const float*)d_in[3];
  const float* bk  = (const float*)d_in[4];
  float* out = (float*)d_out;

  char* ws = (char*)d_ws;
  unsigned short* Wf  = (unsigned short*)ws;             // 1 MiB frag-layout weights
  float* acc          = (float*)(ws + (1 << 20));        // 64 B accumulators
  unsigned short* Afb = (unsigned short*)(ws + (1 << 20) + 256);   // 159.4 MB frag eeg

  hipMemsetAsync(acc, 0, 64, stream);
  k_convw<<<256, 256, 0, stream>>>(wq, wk, Wf);
  k_conva<<<(155648 / 16) * 4, 256, 0, stream>>>(eeg, Afb);   // 9728 m-tiles
  k_fgemm<<<4096, 512, 0, stream>>>(Afb, Wf, bq, bk, acc);
  k_fin<<<1, 64, 0, stream>>>(acc, out);
}

// Round 18
// 378.760 us; speedup vs baseline: 1.3777x; 1.1192x over previous
//
#include <hip/hip_runtime.h>

// ---------- types ----------
typedef short s16x8 __attribute__((ext_vector_type(8)));   // 8 bf16 (4 VGPRs)
typedef float f32x4 __attribute__((ext_vector_type(4)));

static __device__ __forceinline__ unsigned short f2bf(float f) {
  unsigned u = __builtin_bit_cast(unsigned, f);
  return (unsigned short)((u + 0x7FFFu + ((u >> 16) & 1u)) >> 16);   // RNE; finite
}

// async global->LDS, 16B per lane; LDS dst is wave-uniform base + lane*16
#define GLL16(G, L) __builtin_amdgcn_global_load_lds( \
    (const __attribute__((address_space(1))) void*)(G), \
    (__attribute__((address_space(3))) void*)(L), 16, 0, 0)

#define KD 512
// B=16, T=512, C=19, E=512, H=8, HD=64; groups = 8192, rows = 155648 = 1024*152.
// Afb layout: half-block hb (152 rows, padded to 160 = 10 frags of 16 rows);
// frag (hb, f, kt) = 1 KB at ((hb*10 + f)*16 + kt)*512 shorts; within-frag lane
// lf = (row&15) + 16*jc holds 16 B of [row][kt*32 + jc*8]. Reads lane*16-linear.

// ---------- kernel: eeg fp32 -> bf16 half-block fragment layout ----------
__global__ __launch_bounds__(256)
void k_conva(const float* __restrict__ src, unsigned short* __restrict__ dst) {
  long gid = (long)blockIdx.x * 256 + threadIdx.x;   // 10,485,760 threads
  int lane = (int)(gid & 63);
  long rest = gid >> 6;
  int kt = (int)(rest & 15); rest >>= 4;
  int f  = (int)(rest % 10);
  int hb = (int)(rest / 10);
  int row_l = f * 16 + (lane & 15);
  int jc = lane >> 4;
  s16x8 o = (s16x8){0, 0, 0, 0, 0, 0, 0, 0};
  if (row_l < 152) {                       // pad rows 152..159 zeroed (never scored)
    const float* p = src + ((long)hb * 152 + row_l) * KD + kt * 32 + jc * 8;
    float4 v0 = *(const float4*)p;
    float4 v1 = *(const float4*)(p + 4);
    o[0]=(short)f2bf(v0.x); o[1]=(short)f2bf(v0.y); o[2]=(short)f2bf(v0.z); o[3]=(short)f2bf(v0.w);
    o[4]=(short)f2bf(v1.x); o[5]=(short)f2bf(v1.y); o[6]=(short)f2bf(v1.z); o[7]=(short)f2bf(v1.w);
  }
  *(s16x8*)(dst + gid * 8) = o;            // fully coalesced 16 B/lane
}

// ---------- kernel: weights fp32 -> bf16 fragment layout (rows 0..511 wq, 512..1023 wk) ----------
__global__ __launch_bounds__(256)
void k_convw(const float* __restrict__ wq, const float* __restrict__ wk,
             unsigned short* __restrict__ Wf) {
  int gid = blockIdx.x * 256 + threadIdx.x;   // 65536 threads
  int nt = gid >> 10, slot = gid & 1023;
  int kt = slot >> 6, lf = slot & 63;
  int f  = nt * 16 + (lf & 15);
  int jc = lf >> 4;
  const float* p = ((f < 512) ? (wq + (long)f * KD) : (wk + (long)(f - 512) * KD)) + kt * 32 + jc * 8;
  float4 v0 = *(const float4*)p;
  float4 v1 = *(const float4*)(p + 4);
  s16x8 o;
  o[0]=(short)f2bf(v0.x); o[1]=(short)f2bf(v0.y); o[2]=(short)f2bf(v0.z); o[3]=(short)f2bf(v0.w);
  o[4]=(short)f2bf(v1.x); o[5]=(short)f2bf(v1.y); o[6]=(short)f2bf(v1.z); o[7]=(short)f2bf(v1.w);
  *(s16x8*)(Wf + ((long)nt * 16 + kt) * 512 + (long)lf * 8) = o;
}

// CL access: 160 rows x 128 shorts (256 B stride), XOR-swizzled byte ^= (row&7)<<4.
// Written by VALU stores, read by ds_read (both swizzled: rule-21 clean).
#define CL_RD(ROW, CSH) (*(const s16x8*)((const char*)CL + (ROW) * 256 + ((((CSH) * 2)) ^ ((((ROW) & 7)) << 4))))
#define CL_WR(ROW, CSH, V) (*(unsigned short*)((char*)CL + (ROW) * 256 + ((((CSH) * 2)) ^ ((((ROW) & 7)) << 4))) = (V))

// ---------- fused kernel: projection GEMM + scores + softmax, 8 groups / block ----------
// Block = (hb, head h): 152 rows (10 frags) x head h's Q|K (8 n-frags). 2 blocks/CU
// (77.9 KB LDS, ~110 regs): resident blocks cover each other's staging drains (m114)
// -- R17's single lever (it ran 1 block/CU at MfmaUtil 21%).
__global__ __launch_bounds__(512, 4)
void k_fgemm(const unsigned short* __restrict__ Af, const unsigned short* __restrict__ Wf,
             const float* __restrict__ bq, const float* __restrict__ bk,
             float* __restrict__ oacc) {
  __shared__ unsigned short Sbuf[2][18 * 512];   // A frags 0..9, B frags 10..17 (36.9 KB)
  __shared__ unsigned short CL[160 * 128];       // 40 KB, swizzled
  __shared__ float red[8];

  const int tid  = threadIdx.x;
  const int lane = tid & 63;
  const int wid  = tid >> 6;        // 0..7
  const int wm   = wid >> 2;        // 0..1: owns m-frags wm*5 .. wm*5+4
  const int wn   = wid & 3;         // 0..3: owns n-frags wn*2, wn*2+1
  const int rlo  = lane & 15, rhi = lane >> 4;

  // XCD-chunked swizzle: grid 8192 (%8==0, bijective); h fastest -> the 8 head-
  // blocks of one hb run temporally adjacent on ONE XCD (A panel L2-resident).
  const int cpx = gridDim.x >> 3;
  const int L   = ((int)blockIdx.x & 7) * cpx + ((int)blockIdx.x >> 3);
  const int hb  = L >> 3;           // 0..1023
  const int h   = L & 7;

#define STAGE(T, BUF) do { \
    if (wid < 5) { \
      int f0 = wid * 2; \
      GLL16(Af + ((long)(hb * 10 + f0) * 16 + (T)) * 512 + lane * 8, &Sbuf[(BUF)][f0 * 512]); \
      GLL16(Af + ((long)(hb * 10 + f0 + 1) * 16 + (T)) * 512 + lane * 8, &Sbuf[(BUF)][(f0 + 1) * 512]); \
    } else { \
      int ns0 = (wid - 5) * 3; \
      int cnt = (wid == 7) ? 2 : 3; \
      _Pragma("unroll") for (int s = 0; s < 3; ++s) { \
        if (s < cnt) { \
          int ns = ns0 + s; \
          int nt = (ns < 4) ? (h * 4 + ns) : (32 + h * 4 + (ns - 4)); \
          GLL16(Wf + ((long)nt * 16 + (T)) * 512 + lane * 8, &Sbuf[(BUF)][(10 + ns) * 512]); \
        } \
      } \
    } \
  } while (0)

  f32x4 acc[5][2] = {};
  STAGE(0, 0);
  __syncthreads();   // vmcnt(0) drain: buf0 ready

#pragma unroll 1
  for (int t = 0; t < 16; ++t) {
    const int cur = t & 1;
    if (t < 15) STAGE(t + 1, cur ^ 1);   // in flight across the compute phase

    s16x8 bf0 = *(const s16x8*)&Sbuf[cur][(10 + wn * 2) * 512 + lane * 8];
    s16x8 bf1 = *(const s16x8*)&Sbuf[cur][(10 + wn * 2 + 1) * 512 + lane * 8];
#pragma unroll
    for (int i = 0; i < 5; ++i) {
      s16x8 af = *(const s16x8*)&Sbuf[cur][(wm * 5 + i) * 512 + lane * 8];
      acc[i][0] = __builtin_amdgcn_mfma_f32_16x16x32_bf16(af, bf0, acc[i][0], 0, 0, 0);
      acc[i][1] = __builtin_amdgcn_mfma_f32_16x16x32_bf16(af, bf1, acc[i][1], 0, 0, 0);
    }
    if (t < 15) __syncthreads();
  }
#undef STAGE

  // ---- C -> CL (bias + bf16, swizzled); rows fi*16+rhi*4+j < 160 ----
#pragma unroll
  for (int n = 0; n < 2; ++n) {
    int nf = wn * 2 + n;
    int c  = nf * 16 + rlo;
    float bias = (nf < 4) ? bq[h * 64 + c] : bk[h * 64 + (c - 64)];
#pragma unroll
    for (int i = 0; i < 5; ++i) {
      int rbase = (wm * 5 + i) * 16 + rhi * 4;
#pragma unroll
      for (int j = 0; j < 4; ++j)
        CL_WR(rbase + j, c, f2bf(acc[i][n][j] + bias));
    }
  }
  __syncthreads();

  // ---- scores + softmax (verified v3 math): wave wid = group wid ----
  float psum = 0.f;
  {
    const int g19 = wid * 19;        // rows g19 .. g19+18 (max 151)
    const s16x8 z8 = {};
    f32x4 s[2][2] = {};              // [k-tile mi][q-tile nj]
#pragma unroll
    for (int ks = 0; ks < 2; ++ks) {
      s16x8 kb[2], qa[2];
#pragma unroll
      for (int mi = 0; mi < 2; ++mi) {
        int r = mi * 16 + rlo;
        kb[mi] = (r < 19) ? CL_RD(g19 + r, 64 + ks * 32 + rhi * 8) : z8;
        qa[mi] = (r < 19) ? CL_RD(g19 + r, ks * 32 + rhi * 8) : z8;
      }
#pragma unroll
      for (int mi = 0; mi < 2; ++mi)
#pragma unroll
        for (int nj = 0; nj < 2; ++nj)
          s[mi][nj] = __builtin_amdgcn_mfma_f32_16x16x32_bf16(kb[mi], qa[nj], s[mi][nj], 0, 0, 0);
    }
    // lane view: q = nj*16 + rlo; k = mi*16 + rhi*4 + j
#pragma unroll
    for (int nj = 0; nj < 2; ++nj) {
      const int q = nj * 16 + rlo;
      const bool qv = (q < 19);
      const bool wv = (rhi == 0);          // k=16..18 live on rhi==0 (j<3)
      float v0 = s[0][nj][0] * 0.125f;
      float v1 = s[0][nj][1] * 0.125f;
      float v2 = s[0][nj][2] * 0.125f;
      float v3 = s[0][nj][3] * 0.125f;
      float w0 = s[1][nj][0] * 0.125f;
      float w1 = s[1][nj][1] * 0.125f;
      float w2 = s[1][nj][2] * 0.125f;
      float mm = fmaxf(fmaxf(v0, v1), fmaxf(v2, v3));
      if (wv) mm = fmaxf(mm, fmaxf(fmaxf(w0, w1), w2));
      mm = fmaxf(mm, __shfl_xor(mm, 16));
      mm = fmaxf(mm, __shfl_xor(mm, 32));
      float e0 = __expf(v0 - mm), e1 = __expf(v1 - mm);
      float e2 = __expf(v2 - mm), e3 = __expf(v3 - mm);
      float se = e0 + e1 + e2 + e3;
      int k0 = rhi * 4;
      float ue = ((k0 > q) ? e0 : 0.f) + ((k0 + 1 > q) ? e1 : 0.f)
               + ((k0 + 2 > q) ? e2 : 0.f) + ((k0 + 3 > q) ? e3 : 0.f);
      if (wv) {
        float f0 = __expf(w0 - mm), f1 = __expf(w1 - mm), f2 = __expf(w2 - mm);
        se += f0 + f1 + f2;
        ue += ((16 > q) ? f0 : 0.f) + ((17 > q) ? f1 : 0.f) + ((18 > q) ? f2 : 0.f);
      }
      se += __shfl_xor(se, 16); se += __shfl_xor(se, 32);
      ue += __shfl_xor(ue, 16); ue += __shfl_xor(ue, 32);
      if (qv && rhi == 0) psum += ue / se;
    }
  }

  psum += __shfl_xor(psum, 1);
  psum += __shfl_xor(psum, 2);
  psum += __shfl_xor(psum, 4);
  psum += __shfl_xor(psum, 8);
  psum += __shfl_xor(psum, 16);
  psum += __shfl_xor(psum, 32);
  if (lane == 0) red[wid] = psum;
  __syncthreads();
  if (tid == 0) {
    // all 8 groups of this block share batch b = (hb*8)/512 = hb>>6
    atomicAdd(&oacc[hb >> 6], red[0] + red[1] + red[2] + red[3]
                            + red[4] + red[5] + red[6] + red[7]);
  }
}

// ---------- kernel: finalize out[b] = clip(acc[b] / (8*171*512), 0, 1) ----------
__global__ void k_fin(const float* __restrict__ acc, float* __restrict__ out) {
  int t = threadIdx.x;
  if (t < 16) {
    float v = acc[t] * (1.0f / 700416.0f);
    out[t] = fminf(1.0f, fmaxf(0.0f, v));
  }
}

// ---------- host ----------
extern "C" void kernel_launch(void* const* d_in, const int* in_sizes, int n_in,
                              void* d_out, int out_size, void* d_ws, size_t ws_size,
                              hipStream_t stream) {
  const float* eeg = (const float*)d_in[0];
  const float* wq  = (const float*)d_in[1];
  const float* wk  = (const float*)d_in[2];
  const float* bq  = (const float*)d_in[3];
  const float* bk  = (const float*)d_in[4];
  float* out = (float*)d_out;

  char* ws = (char*)d_ws;
  unsigned short* Wf  = (unsigned short*)ws;                       // 1 MiB weights
  float* acc          = (float*)(ws + (1 << 20));                  // 64 B accumulators
  unsigned short* Afb = (unsigned short*)(ws + (1 << 20) + 256);   // 167.8 MB frag eeg

  hipMemsetAsync(acc, 0, 64, stream);
  k_convw<<<256, 256, 0, stream>>>(wq, wk, Wf);
  k_conva<<<40960, 256, 0, stream>>>(eeg, Afb);   // 1024 hb x 10 f x 16 kt frags
  k_fgemm<<<8192, 512, 0, stream>>>(Afb, Wf, bq, bk, acc);
  k_fin<<<1, 64, 0, stream>>>(acc, out);
}

// Round 19
// 329.438 us; speedup vs baseline: 1.5840x; 1.1497x over previous
//
#include <hip/hip_runtime.h>

// ---------- types ----------
typedef short s16x8 __attribute__((ext_vector_type(8)));   // 8 bf16 (4 VGPRs)
typedef float f32x4 __attribute__((ext_vector_type(4)));

static __device__ __forceinline__ unsigned short f2bf(float f) {
  unsigned u = __builtin_bit_cast(unsigned, f);
  return (unsigned short)((u + 0x7FFFu + ((u >> 16) & 1u)) >> 16);   // RNE; finite
}

// async global->LDS, 16B per lane; LDS dst is wave-uniform base + lane*16
#define GLL16(G, L) __builtin_amdgcn_global_load_lds( \
    (const __attribute__((address_space(1))) void*)(G), \
    (__attribute__((address_space(3))) void*)(L), 16, 0, 0)

#define KD 512
// B=16, T=512, C=19, E=512, H=8, HD=64; groups = 8192, rows = 155648 = 1024*152.
// Afb layout: half-block hb (152 rows, padded to 160 = 10 frags of 16 rows);
// frag (hb, f, kt) = 1 KB at ((hb*10 + f)*16 + kt)*512 shorts; within-frag lane
// lf = (row&15) + 16*jc holds 16 B of [row][kt*32 + jc*8]. Reads lane*16-linear.

// ---------- kernel: eeg fp32 -> bf16 half-block fragment layout ----------
__global__ __launch_bounds__(256)
void k_conva(const float* __restrict__ src, unsigned short* __restrict__ dst) {
  long gid = (long)blockIdx.x * 256 + threadIdx.x;   // 10,485,760 threads
  int lane = (int)(gid & 63);
  long rest = gid >> 6;
  int kt = (int)(rest & 15); rest >>= 4;
  int f  = (int)(rest % 10);
  int hb = (int)(rest / 10);
  int row_l = f * 16 + (lane & 15);
  int jc = lane >> 4;
  s16x8 o = (s16x8){0, 0, 0, 0, 0, 0, 0, 0};
  if (row_l < 152) {                       // pad rows 152..159 zeroed (never scored)
    const float* p = src + ((long)hb * 152 + row_l) * KD + kt * 32 + jc * 8;
    float4 v0 = *(const float4*)p;
    float4 v1 = *(const float4*)(p + 4);
    o[0]=(short)f2bf(v0.x); o[1]=(short)f2bf(v0.y); o[2]=(short)f2bf(v0.z); o[3]=(short)f2bf(v0.w);
    o[4]=(short)f2bf(v1.x); o[5]=(short)f2bf(v1.y); o[6]=(short)f2bf(v1.z); o[7]=(short)f2bf(v1.w);
  }
  *(s16x8*)(dst + gid * 8) = o;            // fully coalesced 16 B/lane
}

// ---------- kernel: weights fp32 -> bf16 fragment layout (rows 0..511 wq, 512..1023 wk) ----------
__global__ __launch_bounds__(256)
void k_convw(const float* __restrict__ wq, const float* __restrict__ wk,
             unsigned short* __restrict__ Wf) {
  int gid = blockIdx.x * 256 + threadIdx.x;   // 65536 threads
  int nt = gid >> 10, slot = gid & 1023;
  int kt = slot >> 6, lf = slot & 63;
  int f  = nt * 16 + (lf & 15);
  int jc = lf >> 4;
  const float* p = ((f < 512) ? (wq + (long)f * KD) : (wk + (long)(f - 512) * KD)) + kt * 32 + jc * 8;
  float4 v0 = *(const float4*)p;
  float4 v1 = *(const float4*)(p + 4);
  s16x8 o;
  o[0]=(short)f2bf(v0.x); o[1]=(short)f2bf(v0.y); o[2]=(short)f2bf(v0.z); o[3]=(short)f2bf(v0.w);
  o[4]=(short)f2bf(v1.x); o[5]=(short)f2bf(v1.y); o[6]=(short)f2bf(v1.z); o[7]=(short)f2bf(v1.w);
  *(s16x8*)(Wf + ((long)nt * 16 + kt) * 512 + (long)lf * 8) = o;
}

// CL access: 160 rows x 128 shorts (256 B stride), XOR-swizzled byte ^= (row&7)<<4.
// Written by VALU stores, read by ds_read (both swizzled: rule-21 clean).
#define CL_RD(ROW, CSH) (*(const s16x8*)((const char*)CL + (ROW) * 256 + ((((CSH) * 2)) ^ ((((ROW) & 7)) << 4))))
#define CL_WR(ROW, CSH, V) (*(unsigned short*)((char*)CL + (ROW) * 256 + ((((CSH) * 2)) ^ ((((ROW) & 7)) << 4))) = (V))

// ---------- fused kernel: projection GEMM + scores + softmax, 8 groups / block ----------
// v2 (R19): BK=64, 8 K-steps, ONE barrier per step (8 drain events, was 16).
// LDS union makes it fit at 2 blocks/CU: SL = Sbuf[2][36 frags] (73.7 KB) during the
// K-loop, reused as CL (40 KB) after it (barrier separates last read from overwrite).
// Per-step in-flight window: 20 MFMA + 14 ds_read (~400 cyc) covers the L3-latency
// of the 4-5 GLL16s issued at step top.
__global__ __launch_bounds__(512, 4)
void k_fgemm(const unsigned short* __restrict__ Af, const unsigned short* __restrict__ Wf,
             const float* __restrict__ bq, const float* __restrict__ bk,
             float* __restrict__ oacc) {
  __shared__ unsigned short SL[36864];   // 73,728 B: Sbuf[2][36*512] union CL[160*128]
  __shared__ float red[8];
  unsigned short* CL = SL;               // alias (valid after post-loop barrier)

  const int tid  = threadIdx.x;
  const int lane = tid & 63;
  const int wid  = tid >> 6;        // 0..7
  const int wm   = wid >> 2;        // 0..1: owns m-frags wm*5 .. wm*5+4
  const int wn   = wid & 3;         // 0..3: owns n-frags wn*2, wn*2+1
  const int rlo  = lane & 15, rhi = lane >> 4;

  // XCD-chunked swizzle: grid 8192 (%8==0, bijective); h fastest -> the 8 head-
  // blocks of one hb run temporally adjacent on ONE XCD (A panel L2-resident).
  const int cpx = gridDim.x >> 3;
  const int L   = ((int)blockIdx.x & 7) * cpx + ((int)blockIdx.x >> 3);
  const int hb  = L >> 3;           // 0..1023
  const int h   = L & 7;

  // Buffer b at SL + b*18432 shorts; frag q (0..35) at +q*512. Slot s: fi = s>>1
  // (0..9 A-frag, 10..17 B-frag), half = s&1 -> kt = 2*T + half, dst frag q = s.
#define STAGE(T, BUF) do { \
    unsigned short* bufp = SL + (BUF) * 18432; \
    _Pragma("unroll") for (int k = 0; k < 5; ++k) { \
      int s = wid + 8 * k; \
      if (s < 36) { \
        int fi = s >> 1, half = s & 1; \
        const unsigned short* g; \
        if (fi < 10) { \
          g = Af + ((long)(hb * 10 + fi) * 16 + 2 * (T) + half) * 512 + lane * 8; \
        } else { \
          int ns = fi - 10; \
          int nt = (ns < 4) ? (h * 4 + ns) : (32 + h * 4 + (ns - 4)); \
          g = Wf + ((long)nt * 16 + 2 * (T) + half) * 512 + lane * 8; \
        } \
        GLL16(g, bufp + s * 512); \
      } \
    } \
  } while (0)

  f32x4 acc[5][2] = {};
  STAGE(0, 0);
  __syncthreads();   // vmcnt(0) drain: buf0 ready

#pragma unroll 1
  for (int t = 0; t < 8; ++t) {
    const int cur = t & 1;
    if (t < 7) STAGE(t + 1, cur ^ 1);   // 4-5 GLL16/wave, fly across 20-MFMA phase
    const unsigned short* bufp = SL + cur * 18432;

#pragma unroll
    for (int hh = 0; hh < 2; ++hh) {
      s16x8 bf0 = *(const s16x8*)(bufp + ((10 + wn * 2) * 2 + hh) * 512 + lane * 8);
      s16x8 bf1 = *(const s16x8*)(bufp + ((10 + wn * 2 + 1) * 2 + hh) * 512 + lane * 8);
#pragma unroll
      for (int i = 0; i < 5; ++i) {
        s16x8 af = *(const s16x8*)(bufp + ((wm * 5 + i) * 2 + hh) * 512 + lane * 8);
        acc[i][0] = __builtin_amdgcn_mfma_f32_16x16x32_bf16(af, bf0, acc[i][0], 0, 0, 0);
        acc[i][1] = __builtin_amdgcn_mfma_f32_16x16x32_bf16(af, bf1, acc[i][1], 0, 0, 0);
      }
    }
    if (t < 7) __syncthreads();
  }
#undef STAGE
  __syncthreads();   // all waves done reading SL -> safe to overwrite as CL

  // ---- C -> CL (bias + bf16, swizzled); rows fi*16+rhi*4+j < 160 ----
#pragma unroll
  for (int n = 0; n < 2; ++n) {
    int nf = wn * 2 + n;
    int c  = nf * 16 + rlo;
    float bias = (nf < 4) ? bq[h * 64 + c] : bk[h * 64 + (c - 64)];
#pragma unroll
    for (int i = 0; i < 5; ++i) {
      int rbase = (wm * 5 + i) * 16 + rhi * 4;
#pragma unroll
      for (int j = 0; j < 4; ++j)
        CL_WR(rbase + j, c, f2bf(acc[i][n][j] + bias));
    }
  }
  __syncthreads();

  // ---- scores + softmax (verified v3 math): wave wid = group wid ----
  float psum = 0.f;
  {
    const int g19 = wid * 19;        // rows g19 .. g19+18 (max 151)
    const s16x8 z8 = {};
    f32x4 s[2][2] = {};              // [k-tile mi][q-tile nj]
#pragma unroll
    for (int ks = 0; ks < 2; ++ks) {
      s16x8 kb[2], qa[2];
#pragma unroll
      for (int mi = 0; mi < 2; ++mi) {
        int r = mi * 16 + rlo;
        kb[mi] = (r < 19) ? CL_RD(g19 + r, 64 + ks * 32 + rhi * 8) : z8;
        qa[mi] = (r < 19) ? CL_RD(g19 + r, ks * 32 + rhi * 8) : z8;
      }
#pragma unroll
      for (int mi = 0; mi < 2; ++mi)
#pragma unroll
        for (int nj = 0; nj < 2; ++nj)
          s[mi][nj] = __builtin_amdgcn_mfma_f32_16x16x32_bf16(kb[mi], qa[nj], s[mi][nj], 0, 0, 0);
    }
    // lane view: q = nj*16 + rlo; k = mi*16 + rhi*4 + j
#pragma unroll
    for (int nj = 0; nj < 2; ++nj) {
      const int q = nj * 16 + rlo;
      const bool qv = (q < 19);
      const bool wv = (rhi == 0);          // k=16..18 live on rhi==0 (j<3)
      float v0 = s[0][nj][0] * 0.125f;
      float v1 = s[0][nj][1] * 0.125f;
      float v2 = s[0][nj][2] * 0.125f;
      float v3 = s[0][nj][3] * 0.125f;
      float w0 = s[1][nj][0] * 0.125f;
      float w1 = s[1][nj][1] * 0.125f;
      float w2 = s[1][nj][2] * 0.125f;
      float mm = fmaxf(fmaxf(v0, v1), fmaxf(v2, v3));
      if (wv) mm = fmaxf(mm, fmaxf(fmaxf(w0, w1), w2));
      mm = fmaxf(mm, __shfl_xor(mm, 16));
      mm = fmaxf(mm, __shfl_xor(mm, 32));
      float e0 = __expf(v0 - mm), e1 = __expf(v1 - mm);
      float e2 = __expf(v2 - mm), e3 = __expf(v3 - mm);
      float se = e0 + e1 + e2 + e3;
      int k0 = rhi * 4;
      float ue = ((k0 > q) ? e0 : 0.f) + ((k0 + 1 > q) ? e1 : 0.f)
               + ((k0 + 2 > q) ? e2 : 0.f) + ((k0 + 3 > q) ? e3 : 0.f);
      if (wv) {
        float f0 = __expf(w0 - mm), f1 = __expf(w1 - mm), f2 = __expf(w2 - mm);
        se += f0 + f1 + f2;
        ue += ((16 > q) ? f0 : 0.f) + ((17 > q) ? f1 : 0.f) + ((18 > q) ? f2 : 0.f);
      }
      se += __shfl_xor(se, 16); se += __shfl_xor(se, 32);
      ue += __shfl_xor(ue, 16); ue += __shfl_xor(ue, 32);
      if (qv && rhi == 0) psum += ue / se;
    }
  }

  psum += __shfl_xor(psum, 1);
  psum += __shfl_xor(psum, 2);
  psum += __shfl_xor(psum, 4);
  psum += __shfl_xor(psum, 8);
  psum += __shfl_xor(psum, 16);
  psum += __shfl_xor(psum, 32);
  if (lane == 0) red[wid] = psum;
  __syncthreads();
  if (tid == 0) {
    // all 8 groups of this block share batch b = (hb*8)/512 = hb>>6
    atomicAdd(&oacc[hb >> 6], red[0] + red[1] + red[2] + red[3]
                            + red[4] + red[5] + red[6] + red[7]);
  }
}

// ---------- kernel: finalize out[b] = clip(acc[b] / (8*171*512), 0, 1) ----------
__global__ void k_fin(const float* __restrict__ acc, float* __restrict__ out) {
  int t = threadIdx.x;
  if (t < 16) {
    float v = acc[t] * (1.0f / 700416.0f);
    out[t] = fminf(1.0f, fmaxf(0.0f, v));
  }
}

// ---------- host ----------
extern "C" void kernel_launch(void* const* d_in, const int* in_sizes, int n_in,
                              void* d_out, int out_size, void* d_ws, size_t ws_size,
                              hipStream_t stream) {
  const float* eeg = (const float*)d_in[0];
  const float* wq  = (const float*)d_in[1];
  const float* wk  = (const float*)d_in[2];
  const float* bq  = (const float*)d_in[3];
  const float* bk  = (const float*)d_in[4];
  float* out = (float*)d_out;

  char* ws = (char*)d_ws;
  unsigned short* Wf  = (unsigned short*)ws;                       // 1 MiB weights
  float* acc          = (float*)(ws + (1 << 20));                  // 64 B accumulators
  unsigned short* Afb = (unsigned short*)(ws + (1 << 20) + 256);   // 167.8 MB frag eeg

  hipMemsetAsync(acc, 0, 64, stream);
  k_convw<<<256, 256, 0, stream>>>(wq, wk, Wf);
  k_conva<<<40960, 256, 0, stream>>>(eeg, Afb);   // 1024 hb x 10 f x 16 kt frags
  k_fgemm<<<8192, 512, 0, stream>>>(Afb, Wf, bq, bk, acc);
  k_fin<<<1, 64, 0, stream>>>(acc, out);
}

// Round 20
// 316.683 us; speedup vs baseline: 1.6478x; 1.0403x over previous
//
#include <hip/hip_runtime.h>

// ---------- types ----------
typedef short s16x8 __attribute__((ext_vector_type(8)));   // 8 bf16 (4 VGPRs)
typedef float f32x4 __attribute__((ext_vector_type(4)));

static __device__ __forceinline__ unsigned short f2bf(float f) {
  unsigned u = __builtin_bit_cast(unsigned, f);
  return (unsigned short)((u + 0x7FFFu + ((u >> 16) & 1u)) >> 16);   // RNE; finite
}

// async global->LDS, 16B per lane; LDS dst is wave-uniform base + lane*16
#define GLL16(G, L) __builtin_amdgcn_global_load_lds( \
    (const __attribute__((address_space(1))) void*)(G), \
    (__attribute__((address_space(3))) void*)(L), 16, 0, 0)

#define KD 512
// B=16, T=512, C=19, E=512, H=8, HD=64; groups = 8192, rows = 155648 = 1024*152.
// Afb layout: half-block hb (152 rows, padded to 160 = 10 frags of 16 rows);
// frag (hb, f, kt) = 1 KB at ((hb*10 + f)*16 + kt)*512 shorts; within-frag lane
// lf = (row&15) + 16*jc holds 16 B of [row][kt*32 + jc*8]. Reads lane*16-linear.

// ---------- kernel: eeg fp32 -> bf16 half-block fragment layout ----------
__global__ __launch_bounds__(256)
void k_conva(const float* __restrict__ src, unsigned short* __restrict__ dst) {
  long gid = (long)blockIdx.x * 256 + threadIdx.x;   // 10,485,760 threads
  int lane = (int)(gid & 63);
  long rest = gid >> 6;
  int kt = (int)(rest & 15); rest >>= 4;
  int f  = (int)(rest % 10);
  int hb = (int)(rest / 10);
  int row_l = f * 16 + (lane & 15);
  int jc = lane >> 4;
  s16x8 o = (s16x8){0, 0, 0, 0, 0, 0, 0, 0};
  if (row_l < 152) {                       // pad rows 152..159 zeroed (never scored)
    const float* p = src + ((long)hb * 152 + row_l) * KD + kt * 32 + jc * 8;
    float4 v0 = *(const float4*)p;
    float4 v1 = *(const float4*)(p + 4);
    o[0]=(short)f2bf(v0.x); o[1]=(short)f2bf(v0.y); o[2]=(short)f2bf(v0.z); o[3]=(short)f2bf(v0.w);
    o[4]=(short)f2bf(v1.x); o[5]=(short)f2bf(v1.y); o[6]=(short)f2bf(v1.z); o[7]=(short)f2bf(v1.w);
  }
  *(s16x8*)(dst + gid * 8) = o;            // fully coalesced 16 B/lane
}

// ---------- kernel: weights fp32 -> bf16 fragment layout (rows 0..511 wq, 512..1023 wk) ----------
__global__ __launch_bounds__(256)
void k_convw(const float* __restrict__ wq, const float* __restrict__ wk,
             unsigned short* __restrict__ Wf) {
  int gid = blockIdx.x * 256 + threadIdx.x;   // 65536 threads
  int nt = gid >> 10, slot = gid & 1023;
  int kt = slot >> 6, lf = slot & 63;
  int f  = nt * 16 + (lf & 15);
  int jc = lf >> 4;
  const float* p = ((f < 512) ? (wq + (long)f * KD) : (wk + (long)(f - 512) * KD)) + kt * 32 + jc * 8;
  float4 v0 = *(const float4*)p;
  float4 v1 = *(const float4*)(p + 4);
  s16x8 o;
  o[0]=(short)f2bf(v0.x); o[1]=(short)f2bf(v0.y); o[2]=(short)f2bf(v0.z); o[3]=(short)f2bf(v0.w);
  o[4]=(short)f2bf(v1.x); o[5]=(short)f2bf(v1.y); o[6]=(short)f2bf(v1.z); o[7]=(short)f2bf(v1.w);
  *(s16x8*)(Wf + ((long)nt * 16 + kt) * 512 + (long)lf * 8) = o;
}

// CL access: 160 rows x 128 shorts (256 B stride), XOR-swizzled byte ^= (row&7)<<4.
// Written by VALU stores, read by ds_read (both swizzled: rule-21 clean).
#define CL_RD(ROW, CSH) (*(const s16x8*)((const char*)CL + (ROW) * 256 + ((((CSH) * 2)) ^ ((((ROW) & 7)) << 4))))
#define CL_WR(ROW, CSH, V) (*(unsigned short*)((char*)CL + (ROW) * 256 + ((((CSH) * 2)) ^ ((((ROW) & 7)) << 4))) = (V))

// ---------- fused kernel: projection GEMM + scores + softmax, 8 groups / block ----------
// v3 (R20): R19 structure + micro-opts: (1) STAGE global addresses hoisted into
// named per-slot pointers (advance += 1024 shorts/step: constant) -- the K-loop's
// dominant VALU cost was re-computed 64-bit addressing (VALUBusy 42%); (2) static
// per-wave slot counts (no runtime s<36 compare); (3) setprio(1) around MFMA
// clusters (2 independent blocks/CU = role diversity, m191 regime); (4) biases
// pre-loaded before the K-loop.
__global__ __launch_bounds__(512, 4)
void k_fgemm(const unsigned short* __restrict__ Af, const unsigned short* __restrict__ Wf,
             const float* __restrict__ bq, const float* __restrict__ bk,
             float* __restrict__ oacc) {
  __shared__ unsigned short SL[36864];   // 73,728 B: Sbuf[2][36*512] union CL[160*128]
  __shared__ float red[8];
  unsigned short* CL = SL;               // alias (valid after post-loop barrier)

  const int tid  = threadIdx.x;
  const int lane = tid & 63;
  const int wid  = tid >> 6;        // 0..7
  const int wm   = wid >> 2;        // 0..1: owns m-frags wm*5 .. wm*5+4
  const int wn   = wid & 3;         // 0..3: owns n-frags wn*2, wn*2+1
  const int rlo  = lane & 15, rhi = lane >> 4;

  // XCD-chunked swizzle: grid 8192 (%8==0, bijective); h fastest -> the 8 head-
  // blocks of one hb run temporally adjacent on ONE XCD (A panel L2-resident).
  const int cpx = gridDim.x >> 3;
  const int L   = ((int)blockIdx.x & 7) * cpx + ((int)blockIdx.x >> 3);
  const int hb  = L >> 3;           // 0..1023
  const int h   = L & 7;

  // ---- hoisted staging slots: wave wid owns s = wid + 8k (k < nslot) ----
  // slot s: fi = s>>1 (0..9 A-frag, 10..17 B-frag), half = s&1; per K-step the
  // global address advances by exactly 1024 shorts (2 KB). Static indices only.
  const unsigned short* gp0; const unsigned short* gp1; const unsigned short* gp2;
  const unsigned short* gp3; const unsigned short* gp4 = 0;
  unsigned int lo0, lo1, lo2, lo3, lo4 = 0;
#define SLOT_INIT(K, GP, LO) do { \
    int s = wid + 8 * (K); \
    int fi = s >> 1, half = s & 1; \
    if (fi < 10) { \
      GP = Af + ((long)(hb * 10 + fi) * 16 + half) * 512 + lane * 8; \
    } else { \
      int ns = fi - 10; \
      int nt = (ns < 4) ? (h * 4 + ns) : (32 + h * 4 + (ns - 4)); \
      GP = Wf + ((long)nt * 16 + half) * 512 + lane * 8; \
    } \
    LO = s * 512; \
  } while (0)
  SLOT_INIT(0, gp0, lo0);
  SLOT_INIT(1, gp1, lo1);
  SLOT_INIT(2, gp2, lo2);
  SLOT_INIT(3, gp3, lo3);
  if (wid < 4) SLOT_INIT(4, gp4, lo4);
#undef SLOT_INIT

#define STAGE(BUFOFF) do { \
    GLL16(gp0, SL + (BUFOFF) + lo0); gp0 += 1024; \
    GLL16(gp1, SL + (BUFOFF) + lo1); gp1 += 1024; \
    GLL16(gp2, SL + (BUFOFF) + lo2); gp2 += 1024; \
    GLL16(gp3, SL + (BUFOFF) + lo3); gp3 += 1024; \
    if (wid < 4) { GLL16(gp4, SL + (BUFOFF) + lo4); gp4 += 1024; } \
  } while (0)

  // ---- pre-load epilogue biases (latency hidden under K-loop) ----
  float biasv[2];
#pragma unroll
  for (int n = 0; n < 2; ++n) {
    int nf = wn * 2 + n;
    int c  = nf * 16 + rlo;
    biasv[n] = (nf < 4) ? bq[h * 64 + c] : bk[h * 64 + (c - 64)];
  }

  f32x4 acc[5][2] = {};
  STAGE(0);
  __syncthreads();   // vmcnt(0) drain: buf0 ready

#pragma unroll 1
  for (int t = 0; t < 8; ++t) {
    const int curoff = (t & 1) * 18432;
    if (t < 7) STAGE(curoff ^ 18432);   // issue next buffer; flies across 40 MFMA
    const unsigned short* bufp = SL + curoff;

#pragma unroll
    for (int hh = 0; hh < 2; ++hh) {
      s16x8 bf0 = *(const s16x8*)(bufp + ((10 + wn * 2) * 2 + hh) * 512 + lane * 8);
      s16x8 bf1 = *(const s16x8*)(bufp + ((10 + wn * 2 + 1) * 2 + hh) * 512 + lane * 8);
      s16x8 af0 = *(const s16x8*)(bufp + ((wm * 5 + 0) * 2 + hh) * 512 + lane * 8);
      s16x8 af1 = *(const s16x8*)(bufp + ((wm * 5 + 1) * 2 + hh) * 512 + lane * 8);
      s16x8 af2 = *(const s16x8*)(bufp + ((wm * 5 + 2) * 2 + hh) * 512 + lane * 8);
      s16x8 af3 = *(const s16x8*)(bufp + ((wm * 5 + 3) * 2 + hh) * 512 + lane * 8);
      s16x8 af4 = *(const s16x8*)(bufp + ((wm * 5 + 4) * 2 + hh) * 512 + lane * 8);
      __builtin_amdgcn_s_setprio(1);
      acc[0][0] = __builtin_amdgcn_mfma_f32_16x16x32_bf16(af0, bf0, acc[0][0], 0, 0, 0);
      acc[0][1] = __builtin_amdgcn_mfma_f32_16x16x32_bf16(af0, bf1, acc[0][1], 0, 0, 0);
      acc[1][0] = __builtin_amdgcn_mfma_f32_16x16x32_bf16(af1, bf0, acc[1][0], 0, 0, 0);
      acc[1][1] = __builtin_amdgcn_mfma_f32_16x16x32_bf16(af1, bf1, acc[1][1], 0, 0, 0);
      acc[2][0] = __builtin_amdgcn_mfma_f32_16x16x32_bf16(af2, bf0, acc[2][0], 0, 0, 0);
      acc[2][1] = __builtin_amdgcn_mfma_f32_16x16x32_bf16(af2, bf1, acc[2][1], 0, 0, 0);
      acc[3][0] = __builtin_amdgcn_mfma_f32_16x16x32_bf16(af3, bf0, acc[3][0], 0, 0, 0);
      acc[3][1] = __builtin_amdgcn_mfma_f32_16x16x32_bf16(af3, bf1, acc[3][1], 0, 0, 0);
      acc[4][0] = __builtin_amdgcn_mfma_f32_16x16x32_bf16(af4, bf0, acc[4][0], 0, 0, 0);
      acc[4][1] = __builtin_amdgcn_mfma_f32_16x16x32_bf16(af4, bf1, acc[4][1], 0, 0, 0);
      __builtin_amdgcn_s_setprio(0);
    }
    if (t < 7) __syncthreads();
  }
#undef STAGE
  __syncthreads();   // all waves done reading SL -> safe to overwrite as CL

  // ---- C -> CL (bias + bf16, swizzled); rows fi*16+rhi*4+j < 160 ----
#pragma unroll
  for (int n = 0; n < 2; ++n) {
    int c = (wn * 2 + n) * 16 + rlo;
#pragma unroll
    for (int i = 0; i < 5; ++i) {
      int rbase = (wm * 5 + i) * 16 + rhi * 4;
#pragma unroll
      for (int j = 0; j < 4; ++j)
        CL_WR(rbase + j, c, f2bf(acc[i][n][j] + biasv[n]));
    }
  }
  __syncthreads();

  // ---- scores + softmax (verified v3 math): wave wid = group wid ----
  float psum = 0.f;
  {
    const int g19 = wid * 19;        // rows g19 .. g19+18 (max 151)
    const s16x8 z8 = {};
    f32x4 s[2][2] = {};              // [k-tile mi][q-tile nj]
#pragma unroll
    for (int ks = 0; ks < 2; ++ks) {
      s16x8 kb[2], qa[2];
#pragma unroll
      for (int mi = 0; mi < 2; ++mi) {
        int r = mi * 16 + rlo;
        kb[mi] = (r < 19) ? CL_RD(g19 + r, 64 + ks * 32 + rhi * 8) : z8;
        qa[mi] = (r < 19) ? CL_RD(g19 + r, ks * 32 + rhi * 8) : z8;
      }
#pragma unroll
      for (int mi = 0; mi < 2; ++mi)
#pragma unroll
        for (int nj = 0; nj < 2; ++nj)
          s[mi][nj] = __builtin_amdgcn_mfma_f32_16x16x32_bf16(kb[mi], qa[nj], s[mi][nj], 0, 0, 0);
    }
    // lane view: q = nj*16 + rlo; k = mi*16 + rhi*4 + j
#pragma unroll
    for (int nj = 0; nj < 2; ++nj) {
      const int q = nj * 16 + rlo;
      const bool qv = (q < 19);
      const bool wv = (rhi == 0);          // k=16..18 live on rhi==0 (j<3)
      float v0 = s[0][nj][0] * 0.125f;
      float v1 = s[0][nj][1] * 0.125f;
      float v2 = s[0][nj][2] * 0.125f;
      float v3 = s[0][nj][3] * 0.125f;
      float w0 = s[1][nj][0] * 0.125f;
      float w1 = s[1][nj][1] * 0.125f;
      float w2 = s[1][nj][2] * 0.125f;
      float mm = fmaxf(fmaxf(v0, v1), fmaxf(v2, v3));
      if (wv) mm = fmaxf(mm, fmaxf(fmaxf(w0, w1), w2));
      mm = fmaxf(mm, __shfl_xor(mm, 16));
      mm = fmaxf(mm, __shfl_xor(mm, 32));
      float e0 = __expf(v0 - mm), e1 = __expf(v1 - mm);
      float e2 = __expf(v2 - mm), e3 = __expf(v3 - mm);
      float se = e0 + e1 + e2 + e3;
      int k0 = rhi * 4;
      float ue = ((k0 > q) ? e0 : 0.f) + ((k0 + 1 > q) ? e1 : 0.f)
               + ((k0 + 2 > q) ? e2 : 0.f) + ((k0 + 3 > q) ? e3 : 0.f);
      if (wv) {
        float f0 = __expf(w0 - mm), f1 = __expf(w1 - mm), f2 = __expf(w2 - mm);
        se += f0 + f1 + f2;
        ue += ((16 > q) ? f0 : 0.f) + ((17 > q) ? f1 : 0.f) + ((18 > q) ? f2 : 0.f);
      }
      se += __shfl_xor(se, 16); se += __shfl_xor(se, 32);
      ue += __shfl_xor(ue, 16); ue += __shfl_xor(ue, 32);
      if (qv && rhi == 0) psum += ue / se;
    }
  }

  psum += __shfl_xor(psum, 1);
  psum += __shfl_xor(psum, 2);
  psum += __shfl_xor(psum, 4);
  psum += __shfl_xor(psum, 8);
  psum += __shfl_xor(psum, 16);
  psum += __shfl_xor(psum, 32);
  if (lane == 0) red[wid] = psum;
  __syncthreads();
  if (tid == 0) {
    // all 8 groups of this block share batch b = (hb*8)/512 = hb>>6
    atomicAdd(&oacc[hb >> 6], red[0] + red[1] + red[2] + red[3]
                            + red[4] + red[5] + red[6] + red[7]);
  }
}

// ---------- kernel: finalize out[b] = clip(acc[b] / (8*171*512), 0, 1) ----------
__global__ void k_fin(const float* __restrict__ acc, float* __restrict__ out) {
  int t = threadIdx.x;
  if (t < 16) {
    float v = acc[t] * (1.0f / 700416.0f);
    out[t] = fminf(1.0f, fmaxf(0.0f, v));
  }
}

// ---------- host ----------
extern "C" void kernel_launch(void* const* d_in, const int* in_sizes, int n_in,
                              void* d_out, int out_size, void* d_ws, size_t ws_size,
                              hipStream_t stream) {
  const float* eeg = (const float*)d_in[0];
  const float* wq  = (const float*)d_in[1];
  const float* wk  = (const float*)d_in[2];
  const float* bq  = (const float*)d_in[3];
  const float* bk  = (const float*)d_in[4];
  float* out = (float*)d_out;

  char* ws = (char*)d_ws;
  unsigned short* Wf  = (unsigned short*)ws;                       // 1 MiB weights
  float* acc          = (float*)(ws + (1 << 20));                  // 64 B accumulators
  unsigned short* Afb = (unsigned short*)(ws + (1 << 20) + 256);   // 167.8 MB frag eeg

  hipMemsetAsync(acc, 0, 64, stream);
  k_convw<<<256, 256, 0, stream>>>(wq, wk, Wf);
  k_conva<<<40960, 256, 0, stream>>>(eeg, Afb);   // 1024 hb x 10 f x 16 kt frags
  k_fgemm<<<8192, 512, 0, stream>>>(Afb, Wf, bq, bk, acc);
  k_fin<<<1, 64, 0, stream>>>(acc, out);
}